// Round 3
// baseline (1868.820 us; speedup 1.0000x reference)
//
#include <hip/hip_runtime.h>
#include <hip/hip_bf16.h>

// Attention_aux: fused aux-attention scorer + context + output projection.
//   1. convw1:   W1[:, :3072] -> bf16 (ws)
//   2. hbias:    hb[b,d] = hs[b,:]·W1[d,3072:] + b1[d]  (fp32)
//   3. gemm_score: bf16 MFMA  pre = enc·W1a^T ; epilogue p = sum tanh(pre+hb)*w2
//      256x256 tile, BK=64, 8 waves, dbuf LDS, counted vmcnt (T3+T4), raw
//      s_barrier, XOR-swizzled LDS (T2), setprio (T5). A = fp32 reg-staged
//      with cvt_pk; B via global_load_lds (pre-swizzled source).
//   4. softmax over S -> alpha
//   5. ctxpart/ctxreduce: context = alpha^T · enc  (fp32, deterministic)
//   6. final:    out = context·W3^T + b3

typedef float          fx4 __attribute__((ext_vector_type(4)));
typedef short          sv8 __attribute__((ext_vector_type(8)));
typedef unsigned short uv8 __attribute__((ext_vector_type(8)));
typedef unsigned short uv4 __attribute__((ext_vector_type(4)));
typedef unsigned int   ui4 __attribute__((ext_vector_type(4)));

__device__ __forceinline__ unsigned short f2bf(float x) {
  unsigned u = __float_as_uint(x);
  return (unsigned short)((u + 0x7FFFu + ((u >> 16) & 1u)) >> 16);
}

// packed RNE f32x2 -> bf16x2 via HW instruction
__device__ __forceinline__ unsigned cvtpk(float lo, float hi) {
  unsigned r;
  asm("v_cvt_pk_bf16_f32 %0, %1, %2" : "=v"(r) : "v"(lo), "v"(hi));
  return r;
}
__device__ __forceinline__ ui4 pack8(fx4 a, fx4 b) {
  ui4 v;
  v[0] = cvtpk(a[0], a[1]); v[1] = cvtpk(a[2], a[3]);
  v[2] = cvtpk(b[0], b[1]); v[3] = cvtpk(b[2], b[3]);
  return v;
}

// ---------------- kernel 1: convert W1[:, :3072] to bf16 ----------------
__global__ void convw1_kernel(const float* __restrict__ W1, unsigned short* __restrict__ W1a) {
  int id = blockIdx.x * 256 + threadIdx.x;      // float4 id, 1024*768 total
  int d = id / 768, fi = id - d * 768;
  fx4 v = ((const fx4*)W1)[d * 1024 + fi];
  uv4 r; r[0] = f2bf(v[0]); r[1] = f2bf(v[1]); r[2] = f2bf(v[2]); r[3] = f2bf(v[3]);
  ((uv4*)W1a)[d * 768 + fi] = r;
}

// ---------------- kernel 2: hidden-state bias  hb[b,d] ----------------
__global__ void hbias_kernel(const float* __restrict__ hs, const float* __restrict__ W1,
                             const float* __restrict__ b1, float* __restrict__ hb) {
  int idx = (blockIdx.x << 2) + (threadIdx.x >> 6);   // 0..32767 = b*1024+d
  int lane = threadIdx.x & 63;
  int b = idx >> 10, d = idx & 1023;
  const fx4* hv = (const fx4*)hs;
  const fx4* wv = (const fx4*)W1;
  float s = 0.f;
#pragma unroll
  for (int i = 0; i < 4; ++i) {
    int k4 = lane + (i << 6);
    fx4 h = hv[(b << 8) + k4];
    fx4 w = wv[d * 1024 + 768 + k4];
    s += h[0] * w[0] + h[1] * w[1] + h[2] * w[2] + h[3] * w[3];
  }
#pragma unroll
  for (int off = 32; off; off >>= 1) s += __shfl_xor(s, off);
  if (lane == 0) hb[idx] = s + b1[d];
}

// ---------------- kernel 3: big GEMM + tanh·w2 epilogue ----------------
// M=32768, N=1024, K=3072. Block 256x256, BK=64, 8 waves (2M x 4N), each
// wave owns 128x64 of C. Double-buffered LDS, counted vmcnt, raw barriers.
// Per-wave steady-state VMEM queue: A(kt+1) regs [8] then B(kt+1) lds [4].
__global__ __launch_bounds__(512, 2)
void gemm_score(const float* __restrict__ enc,
                const unsigned short* __restrict__ W1a,
                const float* __restrict__ hb,
                const float* __restrict__ w2,
                float* __restrict__ pe) {
  __shared__ __align__(16) unsigned short As[2][16384];   // [256 rows][64 k]
  __shared__ __align__(16) unsigned short Bs[2][16384];   // [256 cols][64 k]

  const int t = threadIdx.x;
  const int lane = t & 63, wid = t >> 6;
  const int wm = wid >> 2, wn = wid & 3;          // 2 x 4 wave grid

  // XCD-bijective swizzle: 512 blocks, XCD x owns lg [x*64, x*64+64)
  const int bid = blockIdx.x;
  const int lg = ((bid & 7) << 6) | (bid >> 3);
  const int mt = lg >> 2, nt = lg & 3;
  const int row0 = mt << 8;            // 256-row M tile (within one batch)
  const int col0 = nt << 8;            // 256-col N tile

  const fx4* encv = (const fx4*)enc;   // enc row = 768 fx4

  // ---- A staging: thread t owns row ar, 128B half ah (32 fp32 contiguous) ----
  const int ar = t >> 1, ah = t & 1;
  const int agb = (row0 + ar) * 768 + ah * 8;     // fx4 index; + kt*16
  const int awb = ar * 64;                        // LDS elem base of row
  int wsl[4];                                     // swizzled 8-elem slot offsets
#pragma unroll
  for (int i = 0; i < 4; ++i) wsl[i] = (((4 * ah + i) ^ (ar & 7)) << 3);

  // ---- B staging: wave wid covers cols 32*wid..+31, 4 gload_lds per tile ----
  // lane l -> col_local = 8i + (l>>3), LDS slot = l&7 (linear dest),
  // source k pre-swizzled: 8*((l&7) ^ ((l>>3)&7))
  const unsigned short* bsrc[4];
  int bdst[4];
#pragma unroll
  for (int i = 0; i < 4; ++i) {
    int col_g = col0 + 32 * wid + 8 * i + (lane >> 3);
    bsrc[i] = W1a + col_g * 3072 + (((lane & 7) ^ ((lane >> 3) & 7)) << 3);
    bdst[i] = (32 * wid + 8 * i) * 64;
  }

  // ---- fragment read offsets (XOR swizzle: slot = (q+4*kh) ^ (row&7)) ----
  const int r15 = lane & 15, q = lane >> 4, r7 = r15 & 7;
  const int baseA0 = (wm * 128 + r15) * 64 + ((q ^ r7) << 3);
  const int baseA1 = (wm * 128 + r15) * 64 + (((q + 4) ^ r7) << 3);
  const int baseB0 = (wn * 64 + r15) * 64 + ((q ^ r7) << 3);
  const int baseB1 = (wn * 64 + r15) * 64 + (((q + 4) ^ r7) << 3);

  fx4 acc[8][4] = {};
  fx4 pa[8];

#define A_LOAD(kt)                                                    \
  { _Pragma("unroll")                                                 \
    for (int j = 0; j < 8; ++j) pa[j] = encv[agb + (kt) * 16 + j]; }
#define A_WRITE(bq)                                                   \
  { _Pragma("unroll")                                                 \
    for (int i = 0; i < 4; ++i)                                       \
      *(ui4*)&As[bq][awb + wsl[i]] = pack8(pa[2 * i], pa[2 * i + 1]); }
#define B_ISSUE(bq, kt)                                               \
  { _Pragma("unroll")                                                 \
    for (int i = 0; i < 4; ++i)                                       \
      __builtin_amdgcn_global_load_lds(                               \
          (const __attribute__((address_space(1))) void*)(bsrc[i] + (kt) * 64), \
          (__attribute__((address_space(3))) void*)&Bs[bq][bdst[i]],  \
          16, 0, 0); }
#define COMPUTE_HALF(p, bA, bB)                                       \
  { sv8 af[8], bfv[4];                                                \
    _Pragma("unroll")                                                 \
    for (int mi = 0; mi < 8; ++mi) af[mi] = *(const sv8*)&As[p][(bA) + mi * 1024]; \
    _Pragma("unroll")                                                 \
    for (int ni = 0; ni < 4; ++ni) bfv[ni] = *(const sv8*)&Bs[p][(bB) + ni * 1024]; \
    __builtin_amdgcn_s_setprio(1);                                    \
    _Pragma("unroll")                                                 \
    for (int mi = 0; mi < 8; ++mi)                                    \
      _Pragma("unroll")                                               \
      for (int ni = 0; ni < 4; ++ni)                                  \
        acc[mi][ni] = __builtin_amdgcn_mfma_f32_16x16x32_bf16(af[mi], bfv[ni], acc[mi][ni], 0, 0, 0); \
    __builtin_amdgcn_s_setprio(0); }

  // ---- prologue: establish dbuf + in-flight invariant ----
  A_LOAD(0)
  B_ISSUE(0, 0)
  A_WRITE(0)                 // compiler gates on pa(0) landing
  A_LOAD(1)
  B_ISSUE(1, 1)
  asm volatile("s_waitcnt lgkmcnt(0)" ::: "memory");
  __builtin_amdgcn_s_barrier();
  asm volatile("s_waitcnt vmcnt(12)" ::: "memory");   // B(0) landed
  __builtin_amdgcn_s_barrier();

  // ---- main loop: 48 K-tiles ----
  for (int kt = 0; kt < 48; ++kt) {
    const int p = kt & 1;
    if (p == 0) { COMPUTE_HALF(0, baseA0, baseB0) COMPUTE_HALF(0, baseA1, baseB1) }
    else        { COMPUTE_HALF(1, baseA0, baseB0) COMPUTE_HALF(1, baseA1, baseB1) }
    if (kt < 47) { A_WRITE(p ^ 1) }      // write A(kt+1); compiler waits its loads
    if (kt < 46) { A_LOAD(kt + 2) }      // issue A(kt+2) regs
    asm volatile("s_waitcnt lgkmcnt(0)" ::: "memory");
    __builtin_amdgcn_s_barrier();        // all waves: done reading buf p, A(kt+1) visible
    __builtin_amdgcn_sched_barrier(0);
    if (kt < 46) { B_ISSUE(p, kt + 2) }  // overwrite Bbuf[p] (reads certified)
    if (kt < 46) {
      asm volatile("s_waitcnt vmcnt(12)" ::: "memory");  // B(kt+1) landed
    } else if (kt == 46) {
      asm volatile("s_waitcnt vmcnt(0)" ::: "memory");   // B(47) landed
    }
    __builtin_amdgcn_s_barrier();        // tile kt+1 certified complete
  }

  // ---- epilogue: p[row] += sum_{cols in tile} tanh(acc + hb) * w2 ----
  // C layout: col = lane&15 (N), row = (lane>>4)*4 + j (M)
  const int b = row0 >> 10;
  float w2v[4], hbv[4];
#pragma unroll
  for (int ni = 0; ni < 4; ++ni) {
    int c = col0 + wn * 64 + ni * 16 + r15;
    w2v[ni] = w2[c];
    hbv[ni] = hb[(b << 10) + c];
  }
#pragma unroll
  for (int mi = 0; mi < 8; ++mi) {
#pragma unroll
    for (int j = 0; j < 4; ++j) {
      float pz = 0.f;
#pragma unroll
      for (int ni = 0; ni < 4; ++ni)
        pz += tanhf(acc[mi][ni][j] + hbv[ni]) * w2v[ni];
      pz += __shfl_xor(pz, 1); pz += __shfl_xor(pz, 2);
      pz += __shfl_xor(pz, 4); pz += __shfl_xor(pz, 8);
      if (r15 == 0) {
        int row = row0 + wm * 128 + mi * 16 + (q << 2) + j;
        pe[(row << 4) + (nt << 2) + wn] = pz;   // 16 deterministic slots/row
      }
    }
  }
#undef A_LOAD
#undef A_WRITE
#undef B_ISSUE
#undef COMPUTE_HALF
}

// ---------------- kernel 4: softmax over S per batch ----------------
__global__ void softmax_kernel(const float* __restrict__ pe, float* __restrict__ alpha) {
  int b = blockIdx.x, t = threadIdx.x;
  int lane = t & 63, wid = t >> 6;
  float ev[4];
#pragma unroll
  for (int r = 0; r < 4; ++r) {
    int s = t + r * 256;
    const float* p = pe + ((b << 10) + s) * 16;
    float sum = 0.f;
#pragma unroll
    for (int i = 0; i < 16; ++i) sum += p[i];
    ev[r] = sum;
  }
  float m = fmaxf(fmaxf(ev[0], ev[1]), fmaxf(ev[2], ev[3]));
#pragma unroll
  for (int off = 32; off; off >>= 1) m = fmaxf(m, __shfl_xor(m, off));
  __shared__ float red[8];
  if (lane == 0) red[wid] = m;
  __syncthreads();
  m = fmaxf(fmaxf(red[0], red[1]), fmaxf(red[2], red[3]));
  float p4[4], ls = 0.f;
#pragma unroll
  for (int r = 0; r < 4; ++r) { p4[r] = expf(ev[r] - m); ls += p4[r]; }
#pragma unroll
  for (int off = 32; off; off >>= 1) ls += __shfl_xor(ls, off);
  if (lane == 0) red[4 + wid] = ls;
  __syncthreads();
  float inv = 1.0f / (red[4] + red[5] + red[6] + red[7]);
#pragma unroll
  for (int r = 0; r < 4; ++r) alpha[(b << 10) + t + r * 256] = p4[r] * inv;
}

// ---------------- kernel 5: context partials over s-chunks ----------------
__global__ void ctxpart_kernel(const float* __restrict__ enc, const float* __restrict__ alpha,
                               float* __restrict__ part) {
  int bid = blockIdx.x, b = bid >> 4, sc = bid & 15;
  int t = threadIdx.x;
  __shared__ float sal[64];
  if (t < 64) sal[t] = alpha[(b << 10) + (sc << 6) + t];
  __syncthreads();
  const fx4* ev = (const fx4*)enc;
  fx4 a0 = {}, a1 = {}, a2 = {};
  int base = ((b << 10) + (sc << 6)) * 768;
  for (int si = 0; si < 64; ++si) {
    float a = sal[si];
    const fx4* rp = ev + base + si * 768;
    a0 += a * rp[t];
    a1 += a * rp[256 + t];
    a2 += a * rp[512 + t];
  }
  fx4* pp = (fx4*)part;
  int pb = ((b << 4) + sc) * 768;
  pp[pb + t] = a0; pp[pb + 256 + t] = a1; pp[pb + 512 + t] = a2;
}

__global__ void ctxreduce_kernel(const float* __restrict__ part, float* __restrict__ ctx) {
  int j = blockIdx.x * 256 + threadIdx.x;     // 0..24575 fx4
  int b = j / 768, fi = j - b * 768;
  const fx4* pp = (const fx4*)part;
  fx4 s = {};
#pragma unroll
  for (int i = 0; i < 16; ++i) s += pp[((b << 4) + i) * 768 + fi];
  ((fx4*)ctx)[b * 768 + fi] = s;
}

// ---------------- kernel 6: out = ctx·W3^T + b3 ----------------
__global__ void final_kernel(const float* __restrict__ ctx, const float* __restrict__ W3,
                             const float* __restrict__ b3, float* __restrict__ out) {
  int idx = (blockIdx.x << 2) + (threadIdx.x >> 6);   // b*1024 + d
  int lane = threadIdx.x & 63;
  int b = idx >> 10, d = idx & 1023;
  const fx4* cv = (const fx4*)ctx;
  const fx4* wv = (const fx4*)W3;
  float s = 0.f;
#pragma unroll
  for (int i = 0; i < 12; ++i) {
    int f4 = lane + (i << 6);
    fx4 c = cv[b * 768 + f4];
    fx4 w = wv[d * 768 + f4];
    s += c[0] * w[0] + c[1] * w[1] + c[2] * w[2] + c[3] * w[3];
  }
#pragma unroll
  for (int off = 32; off; off >>= 1) s += __shfl_xor(s, off);
  if (lane == 0) out[idx] = s + b3[d];
}

extern "C" void kernel_launch(void* const* d_in, const int* in_sizes, int n_in,
                              void* d_out, int out_size, void* d_ws, size_t ws_size,
                              hipStream_t stream) {
  const float* hs  = (const float*)d_in[0];   // (32, 1024)
  const float* enc = (const float*)d_in[1];   // (32, 1024, 3072)
  const float* W1  = (const float*)d_in[2];   // (1024, 4096)
  const float* b1  = (const float*)d_in[3];   // (1024)
  const float* w2  = (const float*)d_in[4];   // (1, 1024)
  const float* W3  = (const float*)d_in[5];   // (1024, 3072)
  const float* b3  = (const float*)d_in[6];   // (1024)
  float* out = (float*)d_out;

  char* ws = (char*)d_ws;                     // ~15.3 MB used, write-before-read
  unsigned short* W1a = (unsigned short*)(ws);          // 6,291,456 B
  float* pe    = (float*)(ws + 6291456);                // 2,097,152 B
  float* alpha = (float*)(ws + 8388608);                // 131,072 B
  float* hb    = (float*)(ws + 8519680);                // 131,072 B
  float* ctx   = (float*)(ws + 8650752);                // 393,216 B
  float* part  = (float*)(ws + 9043968);                // 6,291,456 B

  convw1_kernel<<<3072, 256, 0, stream>>>(W1, W1a);
  hbias_kernel<<<8192, 256, 0, stream>>>(hs, W1, b1, hb);
  gemm_score<<<512, 512, 0, stream>>>(enc, W1a, hb, w2, pe);
  softmax_kernel<<<32, 256, 0, stream>>>(pe, alpha);
  ctxpart_kernel<<<512, 256, 0, stream>>>(enc, alpha, part);
  ctxreduce_kernel<<<96, 256, 0, stream>>>(part, ctx);
  final_kernel<<<8192, 256, 0, stream>>>(ctx, W3, b3, out);
}

// Round 4
// 412.694 us; speedup vs baseline: 4.5283x; 4.5283x over previous
//
#include <hip/hip_runtime.h>
#include <hip/hip_bf16.h>

// Attention_aux: fused aux-attention scorer + context + output projection.
//   1. convw1:   W1[:, :3072] -> bf16 (ws)
//   2. hbias:    hb[b,d] = hs[b,:]·W1[d,3072:] + b1[d]  (fp32)
//   3. gemm_score: bf16 MFMA  pre = enc·W1a^T ; epilogue p = sum tanh(pre+hb)*w2
//      256x256 tile, BK=32 (register-pressure-safe), 8 waves (2Mx4N, wave
//      tile 128x64), dbuf LDS 64KB, counted vmcnt (T3+T4), raw s_barrier,
//      XOR-swizzled LDS (T2), setprio (T5). A = fp32 reg-staged via cvt_pk
//      (pa = 4 fx4 only); B via global_load_lds (pre-swizzled source).
//   4. softmax over S -> alpha
//   5. ctxpart/ctxreduce: context = alpha^T · enc  (fp32, deterministic)
//   6. final:    out = context·W3^T + b3

typedef float          fx4 __attribute__((ext_vector_type(4)));
typedef short          sv8 __attribute__((ext_vector_type(8)));
typedef unsigned short uv4 __attribute__((ext_vector_type(4)));
typedef unsigned int   ui4 __attribute__((ext_vector_type(4)));

__device__ __forceinline__ unsigned short f2bf(float x) {
  unsigned u = __float_as_uint(x);
  return (unsigned short)((u + 0x7FFFu + ((u >> 16) & 1u)) >> 16);
}

// packed RNE f32x2 -> bf16x2 via HW instruction
__device__ __forceinline__ unsigned cvtpk(float lo, float hi) {
  unsigned r;
  asm("v_cvt_pk_bf16_f32 %0, %1, %2" : "=v"(r) : "v"(lo), "v"(hi));
  return r;
}
__device__ __forceinline__ ui4 pack8(fx4 a, fx4 b) {
  ui4 v;
  v[0] = cvtpk(a[0], a[1]); v[1] = cvtpk(a[2], a[3]);
  v[2] = cvtpk(b[0], b[1]); v[3] = cvtpk(b[2], b[3]);
  return v;
}

// ---------------- kernel 1: convert W1[:, :3072] to bf16 ----------------
__global__ void convw1_kernel(const float* __restrict__ W1, unsigned short* __restrict__ W1a) {
  int id = blockIdx.x * 256 + threadIdx.x;      // float4 id, 1024*768 total
  int d = id / 768, fi = id - d * 768;
  fx4 v = ((const fx4*)W1)[d * 1024 + fi];
  uv4 r; r[0] = f2bf(v[0]); r[1] = f2bf(v[1]); r[2] = f2bf(v[2]); r[3] = f2bf(v[3]);
  ((uv4*)W1a)[d * 768 + fi] = r;
}

// ---------------- kernel 2: hidden-state bias  hb[b,d] ----------------
__global__ void hbias_kernel(const float* __restrict__ hs, const float* __restrict__ W1,
                             const float* __restrict__ b1, float* __restrict__ hb) {
  int idx = (blockIdx.x << 2) + (threadIdx.x >> 6);   // 0..32767 = b*1024+d
  int lane = threadIdx.x & 63;
  int b = idx >> 10, d = idx & 1023;
  const fx4* hv = (const fx4*)hs;
  const fx4* wv = (const fx4*)W1;
  float s = 0.f;
#pragma unroll
  for (int i = 0; i < 4; ++i) {
    int k4 = lane + (i << 6);
    fx4 h = hv[(b << 8) + k4];
    fx4 w = wv[d * 1024 + 768 + k4];
    s += h[0] * w[0] + h[1] * w[1] + h[2] * w[2] + h[3] * w[3];
  }
#pragma unroll
  for (int off = 32; off; off >>= 1) s += __shfl_xor(s, off);
  if (lane == 0) hb[idx] = s + b1[d];
}

// ---------------- kernel 3: big GEMM + tanh·w2 epilogue ----------------
// M=32768, N=1024, K=3072. Block 256x256, BK=32, 96 K-iters, 8 waves
// (2M x 4N), wave tile 128x64 (acc 8x4 frags). Double-buffered LDS,
// counted vmcnt, raw barriers. Steady-state per-thread VMEM queue:
// B(kt+1)[2] + A(kt+2)[4] + B(kt+2)[2] = 8 -> wait vmcnt(6) drains B(kt+1).
__global__ __launch_bounds__(512, 2)
void gemm_score(const float* __restrict__ enc,
                const unsigned short* __restrict__ W1a,
                const float* __restrict__ hb,
                const float* __restrict__ w2,
                float* __restrict__ pe) {
  __shared__ __align__(16) unsigned short As[2][8192];   // [256 rows][32 k]
  __shared__ __align__(16) unsigned short Bs[2][8192];   // [256 cols][32 k]

  const int t = threadIdx.x;
  const int lane = t & 63, wid = t >> 6;
  const int wm = wid >> 2, wn = wid & 3;          // 2 x 4 wave grid

  // XCD-bijective swizzle: 512 blocks, XCD x owns lg [x*64, x*64+64)
  const int bid = blockIdx.x;
  const int lg = ((bid & 7) << 6) | (bid >> 3);
  const int mt = lg >> 2, nt = lg & 3;
  const int row0 = mt << 8;            // 256-row M tile
  const int col0 = nt << 8;            // 256-col N tile

  const fx4* encv = (const fx4*)enc;   // enc row = 768 fx4

  // ---- A staging: thread t -> row t>>1, k-half (t&1)*16 floats = 4 fx4 ----
  const int ar = t >> 1, ah = t & 1;
  const int agb = (row0 + ar) * 768 + ah * 4;     // fx4 index; + kt*8
  const int awb = ar * 32;                        // LDS elem base of row
  const int ws0 = ((2 * ah + 0) ^ (ar & 3)) << 3; // swizzled 8-elem slots
  const int ws1 = ((2 * ah + 1) ^ (ar & 3)) << 3;

  // ---- B staging: wave wid covers cols 32*wid..+31; 2 gload_lds/thread ----
  // chunk i: lane l -> col_local = 16i + (l>>2), dest slot l&3 (linear),
  // source k pre-swizzled: slot_src = (l&3) ^ ((l>>2)&3)
  const unsigned short* bsrc0 =
      W1a + (col0 + 32 * wid + (lane >> 2)) * 3072 + (((lane & 3) ^ ((lane >> 2) & 3)) << 3);
  const unsigned short* bsrc1 = bsrc0 + 16 * 3072;
  const int bdst0 = (32 * wid) * 32;
  const int bdst1 = (32 * wid + 16) * 32;

  // ---- fragment read offsets (swizzle: slot = q ^ (row&3)) ----
  const int r15 = lane & 15, q = lane >> 4;
  const int offA = (wm * 128 + r15) * 32 + ((q ^ (r15 & 3)) << 3);  // + mi*512
  const int offB = (wn * 64 + r15) * 32 + ((q ^ (r15 & 3)) << 3);   // + ni*512

  fx4 acc[8][4] = {};
  fx4 pa[4];

#define A_LOAD(kt)                                                    \
  { _Pragma("unroll")                                                 \
    for (int j = 0; j < 4; ++j) pa[j] = encv[agb + (kt) * 8 + j]; }
#define A_WRITE(bq)                                                   \
  { *(ui4*)&As[bq][awb + ws0] = pack8(pa[0], pa[1]);                  \
    *(ui4*)&As[bq][awb + ws1] = pack8(pa[2], pa[3]); }
#define B_ISSUE(bq, kt)                                               \
  { __builtin_amdgcn_global_load_lds(                                 \
        (const __attribute__((address_space(1))) void*)(bsrc0 + (kt) * 32), \
        (__attribute__((address_space(3))) void*)&Bs[bq][bdst0], 16, 0, 0); \
    __builtin_amdgcn_global_load_lds(                                 \
        (const __attribute__((address_space(1))) void*)(bsrc1 + (kt) * 32), \
        (__attribute__((address_space(3))) void*)&Bs[bq][bdst1], 16, 0, 0); }
#define COMPUTE(p)                                                    \
  { sv8 af[8], bfv[4];                                                \
    _Pragma("unroll")                                                 \
    for (int mi = 0; mi < 8; ++mi) af[mi] = *(const sv8*)&As[p][offA + mi * 512]; \
    _Pragma("unroll")                                                 \
    for (int ni = 0; ni < 4; ++ni) bfv[ni] = *(const sv8*)&Bs[p][offB + ni * 512]; \
    __builtin_amdgcn_s_setprio(1);                                    \
    _Pragma("unroll")                                                 \
    for (int mi = 0; mi < 8; ++mi)                                    \
      _Pragma("unroll")                                               \
      for (int ni = 0; ni < 4; ++ni)                                  \
        acc[mi][ni] = __builtin_amdgcn_mfma_f32_16x16x32_bf16(af[mi], bfv[ni], acc[mi][ni], 0, 0, 0); \
    __builtin_amdgcn_s_setprio(0); }
#define ITER(kt, p)                                                   \
  { COMPUTE(p)                                                        \
    if ((kt) < 95) { A_WRITE(p ^ 1) }                                 \
    if ((kt) < 94) { A_LOAD((kt) + 2) }                               \
    asm volatile("s_waitcnt lgkmcnt(0)" ::: "memory");                \
    __builtin_amdgcn_s_barrier();                                     \
    __builtin_amdgcn_sched_barrier(0);                                \
    if ((kt) < 94) {                                                  \
      B_ISSUE(p, (kt) + 2)                                            \
      asm volatile("s_waitcnt vmcnt(6)" ::: "memory");                \
    } else if ((kt) == 94) {                                          \
      asm volatile("s_waitcnt vmcnt(0)" ::: "memory");                \
    }                                                                 \
    __builtin_amdgcn_s_barrier(); }

  // ---- prologue: fill buf0/buf1, establish in-flight invariant ----
  A_LOAD(0)
  B_ISSUE(0, 0)
  A_WRITE(0)                 // compiler inserts vmcnt wait for pa(0)
  A_LOAD(1)
  B_ISSUE(1, 1)
  asm volatile("s_waitcnt lgkmcnt(0)" ::: "memory");
  asm volatile("s_waitcnt vmcnt(6)" ::: "memory");   // B(0) landed
  __builtin_amdgcn_s_barrier();

  // ---- main loop: 96 K-tiles, unrolled x2 for compile-time parity ----
  for (int kt2 = 0; kt2 < 48; ++kt2) {
    const int kt = kt2 * 2;
    ITER(kt, 0)
    ITER(kt + 1, 1)
  }

  // ---- epilogue: p[row] += sum_{cols in tile} tanh(acc + hb) * w2 ----
  // C layout: col = lane&15 (N), row = (lane>>4)*4 + j (M)
  const int b = row0 >> 10;
  float w2v[4], hbv[4];
#pragma unroll
  for (int ni = 0; ni < 4; ++ni) {
    int c = col0 + wn * 64 + ni * 16 + r15;
    w2v[ni] = w2[c];
    hbv[ni] = hb[(b << 10) + c];
  }
#pragma unroll
  for (int mi = 0; mi < 8; ++mi) {
#pragma unroll
    for (int j = 0; j < 4; ++j) {
      float pz = 0.f;
#pragma unroll
      for (int ni = 0; ni < 4; ++ni)
        pz += tanhf(acc[mi][ni][j] + hbv[ni]) * w2v[ni];
      pz += __shfl_xor(pz, 1); pz += __shfl_xor(pz, 2);
      pz += __shfl_xor(pz, 4); pz += __shfl_xor(pz, 8);
      if (r15 == 0) {
        int row = row0 + wm * 128 + mi * 16 + (q << 2) + j;
        pe[(row << 4) + (nt << 2) + wn] = pz;   // 16 deterministic slots/row
      }
    }
  }
#undef A_LOAD
#undef A_WRITE
#undef B_ISSUE
#undef COMPUTE
#undef ITER
}

// ---------------- kernel 4: softmax over S per batch ----------------
__global__ void softmax_kernel(const float* __restrict__ pe, float* __restrict__ alpha) {
  int b = blockIdx.x, t = threadIdx.x;
  int lane = t & 63, wid = t >> 6;
  float ev[4];
#pragma unroll
  for (int r = 0; r < 4; ++r) {
    int s = t + r * 256;
    const float* p = pe + ((b << 10) + s) * 16;
    float sum = 0.f;
#pragma unroll
    for (int i = 0; i < 16; ++i) sum += p[i];
    ev[r] = sum;
  }
  float m = fmaxf(fmaxf(ev[0], ev[1]), fmaxf(ev[2], ev[3]));
#pragma unroll
  for (int off = 32; off; off >>= 1) m = fmaxf(m, __shfl_xor(m, off));
  __shared__ float red[8];
  if (lane == 0) red[wid] = m;
  __syncthreads();
  m = fmaxf(fmaxf(red[0], red[1]), fmaxf(red[2], red[3]));
  float p4[4], ls = 0.f;
#pragma unroll
  for (int r = 0; r < 4; ++r) { p4[r] = expf(ev[r] - m); ls += p4[r]; }
#pragma unroll
  for (int off = 32; off; off >>= 1) ls += __shfl_xor(ls, off);
  if (lane == 0) red[4 + wid] = ls;
  __syncthreads();
  float inv = 1.0f / (red[4] + red[5] + red[6] + red[7]);
#pragma unroll
  for (int r = 0; r < 4; ++r) alpha[(b << 10) + t + r * 256] = p4[r] * inv;
}

// ---------------- kernel 5: context partials over s-chunks ----------------
__global__ void ctxpart_kernel(const float* __restrict__ enc, const float* __restrict__ alpha,
                               float* __restrict__ part) {
  int bid = blockIdx.x, b = bid >> 4, sc = bid & 15;
  int t = threadIdx.x;
  __shared__ float sal[64];
  if (t < 64) sal[t] = alpha[(b << 10) + (sc << 6) + t];
  __syncthreads();
  const fx4* ev = (const fx4*)enc;
  fx4 a0 = {}, a1 = {}, a2 = {};
  int base = ((b << 10) + (sc << 6)) * 768;
  for (int si = 0; si < 64; ++si) {
    float a = sal[si];
    const fx4* rp = ev + base + si * 768;
    a0 += a * rp[t];
    a1 += a * rp[256 + t];
    a2 += a * rp[512 + t];
  }
  fx4* pp = (fx4*)part;
  int pb = ((b << 4) + sc) * 768;
  pp[pb + t] = a0; pp[pb + 256 + t] = a1; pp[pb + 512 + t] = a2;
}

__global__ void ctxreduce_kernel(const float* __restrict__ part, float* __restrict__ ctx) {
  int j = blockIdx.x * 256 + threadIdx.x;     // 0..24575 fx4
  int b = j / 768, fi = j - b * 768;
  const fx4* pp = (const fx4*)part;
  fx4 s = {};
#pragma unroll
  for (int i = 0; i < 16; ++i) s += pp[((b << 4) + i) * 768 + fi];
  ((fx4*)ctx)[b * 768 + fi] = s;
}

// ---------------- kernel 6: out = ctx·W3^T + b3 ----------------
__global__ void final_kernel(const float* __restrict__ ctx, const float* __restrict__ W3,
                             const float* __restrict__ b3, float* __restrict__ out) {
  int idx = (blockIdx.x << 2) + (threadIdx.x >> 6);   // b*1024 + d
  int lane = threadIdx.x & 63;
  int b = idx >> 10, d = idx & 1023;
  const fx4* cv = (const fx4*)ctx;
  const fx4* wv = (const fx4*)W3;
  float s = 0.f;
#pragma unroll
  for (int i = 0; i < 12; ++i) {
    int f4 = lane + (i << 6);
    fx4 c = cv[b * 768 + f4];
    fx4 w = wv[d * 768 + f4];
    s += c[0] * w[0] + c[1] * w[1] + c[2] * w[2] + c[3] * w[3];
  }
#pragma unroll
  for (int off = 32; off; off >>= 1) s += __shfl_xor(s, off);
  if (lane == 0) out[idx] = s + b3[d];
}

extern "C" void kernel_launch(void* const* d_in, const int* in_sizes, int n_in,
                              void* d_out, int out_size, void* d_ws, size_t ws_size,
                              hipStream_t stream) {
  const float* hs  = (const float*)d_in[0];   // (32, 1024)
  const float* enc = (const float*)d_in[1];   // (32, 1024, 3072)
  const float* W1  = (const float*)d_in[2];   // (1024, 4096)
  const float* b1  = (const float*)d_in[3];   // (1024)
  const float* w2  = (const float*)d_in[4];   // (1, 1024)
  const float* W3  = (const float*)d_in[5];   // (1024, 3072)
  const float* b3  = (const float*)d_in[6];   // (1024)
  float* out = (float*)d_out;

  char* ws = (char*)d_ws;                     // ~15.3 MB used, write-before-read
  unsigned short* W1a = (unsigned short*)(ws);          // 6,291,456 B
  float* pe    = (float*)(ws + 6291456);                // 2,097,152 B
  float* alpha = (float*)(ws + 8388608);                // 131,072 B
  float* hb    = (float*)(ws + 8519680);                // 131,072 B
  float* ctx   = (float*)(ws + 8650752);                // 393,216 B
  float* part  = (float*)(ws + 9043968);                // 6,291,456 B

  convw1_kernel<<<3072, 256, 0, stream>>>(W1, W1a);
  hbias_kernel<<<8192, 256, 0, stream>>>(hs, W1, b1, hb);
  gemm_score<<<512, 512, 0, stream>>>(enc, W1a, hb, w2, pe);
  softmax_kernel<<<32, 256, 0, stream>>>(pe, alpha);
  ctxpart_kernel<<<512, 256, 0, stream>>>(enc, alpha, part);
  ctxreduce_kernel<<<96, 256, 0, stream>>>(part, ctx);
  final_kernel<<<8192, 256, 0, stream>>>(ctx, W3, b3, out);
}